// Round 15
// baseline (54.690 us; speedup 1.0000x reference)
//
#include <hip/hip_runtime.h>

typedef unsigned short u16;
typedef short short8 __attribute__((ext_vector_type(8)));
typedef float f32x4 __attribute__((ext_vector_type(4)));

static __device__ __forceinline__ u16 f32_to_bf16(float f) {
  unsigned u = __float_as_uint(f);
  u += 0x7FFFu + ((u >> 16) & 1u);
  return (u16)(u >> 16);
}
static __device__ __forceinline__ float bfLO(unsigned v) { return __uint_as_float(v << 16); }
static __device__ __forceinline__ float bfHI(unsigned v) { return __uint_as_float(v & 0xFFFF0000u); }

static __device__ __forceinline__ void gl_lds16(const void* g, void* l) {
  __builtin_amdgcn_global_load_lds((const __attribute__((address_space(1))) void*)g,
                                   (__attribute__((address_space(3))) void*)l, 16, 0, 0);
}

// ---------------- k0: Wt = W^T (bf16) ; w1 = W@a1, w2 = W@a2 (fp32) ----------------
__global__ __launch_bounds__(256) void k0_prep(const float* __restrict__ W,
                                               const float* __restrict__ a,
                                               u16* __restrict__ Wt,
                                               float* __restrict__ w1,
                                               float* __restrict__ w2) {
  int bid = blockIdx.x;
  int t = threadIdx.x;
  if (bid < 64) {
    __shared__ float tile[64][65];
    int tx = (bid & 7) * 64;   // o (col) base
    int ty = (bid >> 3) * 64;  // k (row) base
    int rl = t >> 4;           // 0..15
    int cb = (t & 15) * 4;     // 0..60
#pragma unroll
    for (int p = 0; p < 4; ++p) {
      float4 v = *(const float4*)(W + (size_t)(ty + rl + p * 16) * 512 + tx + cb);
      tile[rl + p * 16][cb + 0] = v.x;
      tile[rl + p * 16][cb + 1] = v.y;
      tile[rl + p * 16][cb + 2] = v.z;
      tile[rl + p * 16][cb + 3] = v.w;
    }
    __syncthreads();
#pragma unroll
    for (int p = 0; p < 4; ++p) {
      int n = tx + rl + p * 16;
      ushort4 o;
      o.x = f32_to_bf16(tile[cb + 0][rl + p * 16]);
      o.y = f32_to_bf16(tile[cb + 1][rl + p * 16]);
      o.z = f32_to_bf16(tile[cb + 2][rl + p * 16]);
      o.w = f32_to_bf16(tile[cb + 3][rl + p * 16]);
      *(ushort4*)(Wt + (size_t)n * 512 + ty + cb) = o;
    }
  } else {
    int i = (bid - 64) * 4 + (t >> 6);
    int lane = t & 63;
    const float* row = W + (size_t)i * 512;
    float s1 = 0.f, s2 = 0.f;
#pragma unroll
    for (int q = 0; q < 2; ++q) {
      float4 wv = *(const float4*)(row + lane * 8 + q * 4);
      float4 x1 = *(const float4*)(a + lane * 8 + q * 4);
      float4 x2 = *(const float4*)(a + 512 + lane * 8 + q * 4);
      s1 += wv.x * x1.x + wv.y * x1.y + wv.z * x1.z + wv.w * x1.w;
      s2 += wv.x * x2.x + wv.y * x2.y + wv.z * x2.z + wv.w * x2.w;
    }
#pragma unroll
    for (int d = 32; d; d >>= 1) { s1 += __shfl_xor(s1, d); s2 += __shfl_xor(s2, d); }
    if (lane == 0) { w1[i] = s1; w2[i] = s2; }
  }
}

// ---------- k1: es/ed dots (fp32) + hbf = bf16(h), one wave per row ----------------
__global__ __launch_bounds__(256) void k1_rows(const float* __restrict__ h,
                                               const float* __restrict__ w1,
                                               const float* __restrict__ w2,
                                               float* __restrict__ es,
                                               float* __restrict__ ed,
                                               u16* __restrict__ hbf) {
  int r = blockIdx.x * 4 + (threadIdx.x >> 6);
  int lane = threadIdx.x & 63;
  const float* row = h + (size_t)r * 512 + lane * 8;
  float4 v0 = *(const float4*)(row);
  float4 v1 = *(const float4*)(row + 4);
  uint4 pk;
  pk.x = (unsigned)f32_to_bf16(v0.x) | ((unsigned)f32_to_bf16(v0.y) << 16);
  pk.y = (unsigned)f32_to_bf16(v0.z) | ((unsigned)f32_to_bf16(v0.w) << 16);
  pk.z = (unsigned)f32_to_bf16(v1.x) | ((unsigned)f32_to_bf16(v1.y) << 16);
  pk.w = (unsigned)f32_to_bf16(v1.z) | ((unsigned)f32_to_bf16(v1.w) << 16);
  *(uint4*)(hbf + (size_t)r * 512 + lane * 8) = pk;
  float4 x0 = *(const float4*)(w1 + lane * 8);
  float4 x1 = *(const float4*)(w1 + lane * 8 + 4);
  float4 y0 = *(const float4*)(w2 + lane * 8);
  float4 y1 = *(const float4*)(w2 + lane * 8 + 4);
  float s1 = v0.x * x0.x + v0.y * x0.y + v0.z * x0.z + v0.w * x0.w +
             v1.x * x1.x + v1.y * x1.y + v1.z * x1.z + v1.w * x1.w;
  float s2 = v0.x * y0.x + v0.y * y0.y + v0.z * y0.z + v0.w * y0.w +
             v1.x * y1.x + v1.y * y1.y + v1.z * y1.z + v1.w * y1.w;
#pragma unroll
  for (int d = 32; d; d >>= 1) { s1 += __shfl_xor(s1, d); s2 += __shfl_xor(s2, d); }
  if (lane == 0) { es[r] = s1; ed[r] = s2; }
}

// -- k2 fused: [0,2048) adj scan | [2048,2176) ed-sort | [2176,2688) GEMM -----------
// Scan first so BW-bound blocks fill the machine at t=0; compute-bound GEMM blocks
// enter as scan blocks retire and run in the scan's shadow. No intra-launch deps.
__global__ __launch_bounds__(256) void k2_gemm(const u16* __restrict__ hbf,
                                               const u16* __restrict__ Wt,
                                               u16* __restrict__ Whb,
                                               const float* __restrict__ ed,
                                               uint2* __restrict__ edp,
                                               const int* __restrict__ adj,
                                               const float* __restrict__ es,
                                               unsigned* __restrict__ vms_g,
                                               float* __restrict__ ss_g) {
  __shared__ __align__(16) u16 As[2][128 * 32];
  __shared__ __align__(16) u16 Bs[2][64 * 32];
  int t = threadIdx.x;
  int L = blockIdx.x;

  if (L < 2048) {
    // ---- k3a: adj scan -> validity masks + softmax denominator (no-max exp) ----
    // All 16 loads issued into registers BEFORE compute: max memory-level parallelism.
    int q = L;                 // 0..2047
    int wv = t >> 6, lane = t & 63;
    int xcd = q & 7, g = q >> 3;
    int r = (xcd >> 1) * 2048 + (xcd & 1) * 1024 + g * 4 + wv;
    int b = r >> 11;
    float esi = es[r];
    const int4* arow = (const int4*)(adj + ((size_t)r << 11));
    const float4* edr = (const float4*)(ed + ((size_t)b << 11));
    int4 a4[8];
    float4 e4[8];
#pragma unroll
    for (int u = 0; u < 8; ++u) a4[u] = arow[u * 64 + lane];
#pragma unroll
    for (int u = 0; u < 8; ++u) e4[u] = edr[u * 64 + lane];
    unsigned vm = 0;
    float ss = 0.f;
#pragma unroll
    for (int u = 0; u < 8; ++u) {
      float ee[4] = {e4[u].x, e4[u].y, e4[u].z, e4[u].w};
      int aa[4] = {a4[u].x, a4[u].y, a4[u].z, a4[u].w};
#pragma unroll
      for (int c = 0; c < 4; ++c) {
        float xx = esi + ee[c];
        float el = fmaxf(xx, 0.2f * xx);       // LeakyReLU(0.2); |e| <~ 20, exp safe
        bool valid = aa[c] > 0;
        vm |= (valid ? 1u : 0u) << (u * 4 + c);
        ss += valid ? __expf(el) : 0.f;
      }
    }
    vms_g[((size_t)r << 6) + lane] = vm;
#pragma unroll
    for (int d = 32; d; d >>= 1) ss += __shfl_xor(ss, d);
    if (lane == 0) ss_g[r] = ss;
    return;
  }

  if (L < 2176) {
    // ---- batch ed sort by wave-parallel rank-counting ----
    int q = L - 2048;          // 0..127
    int bb = q >> 5;           // batch 0..3
    int seg = q & 31;          // 64-element i-segment
    int lane = t & 63, wvv = t >> 6;
    const float* edb = ed + bb * 2048;
    float4 vals[8];            // this lane's 32 j-values, register-resident
#pragma unroll
    for (int c = 0; c < 8; ++c) vals[c] = *(const float4*)(edb + c * 256 + lane * 4);
    float vk = edb[seg * 64 + wvv * 16 + (lane & 15)];   // prefetch 16 vi per wave
#pragma unroll 1
    for (int k = 0; k < 16; ++k) {
      int i = seg * 64 + wvv * 16 + k;
      float vi = __shfl(vk, k);
      int rank = 0;
#pragma unroll
      for (int c = 0; c < 8; ++c) {
        int jb = c * 256 + lane * 4;
        rank += (int)(vals[c].x > vi) + (int)((vals[c].x == vi) & (jb + 0 < i));
        rank += (int)(vals[c].y > vi) + (int)((vals[c].y == vi) & (jb + 1 < i));
        rank += (int)(vals[c].z > vi) + (int)((vals[c].z == vi) & (jb + 2 < i));
        rank += (int)(vals[c].w > vi) + (int)((vals[c].w == vi) & (jb + 3 < i));
      }
#pragma unroll
      for (int d = 32; d; d >>= 1) rank += __shfl_xor(rank, d);
      if (lane == 0) edp[bb * 2048 + rank] = make_uint2(__float_as_uint(vi), (unsigned)i);
    }
    return;
  }

  int LL = L - 2176;                           // 0..511 (2176 % 8 == 0: XCD map kept)
  int lane = t & 63;
  int wv = t >> 6;
  int xcd = LL & 7, g = LL >> 3;               // XCD swizzle: 8 n-blocks of one m on one XCD
  int m0 = (xcd * 8 + (g >> 3)) * 128;
  int n0 = (g & 7) * 64;
  int wr = (wv >> 1) * 64, wc = (wv & 1) * 32;
  f32x4 zero = {0.f, 0.f, 0.f, 0.f};
  f32x4 acc[4][2];
#pragma unroll
  for (int i = 0; i < 4; ++i)
#pragma unroll
    for (int j = 0; j < 2; ++j) acc[i][j] = zero;
  int kb = (lane >> 4) * 8;
  int mm = lane & 15;
  int sA0 = t, sA1 = t + 256;                  // A: 512 segs of 16B; B: 256 segs
  const u16* gA0 = hbf + (size_t)(m0 + (sA0 >> 2)) * 512 + (sA0 & 3) * 8;
  const u16* gA1 = hbf + (size_t)(m0 + (sA1 >> 2)) * 512 + (sA1 & 3) * 8;
  const u16* gB = Wt + (size_t)(n0 + (t >> 2)) * 512 + (t & 3) * 8;

  gl_lds16(gA0, (char*)As[0] + sA0 * 16);
  gl_lds16(gA1, (char*)As[0] + sA1 * 16);
  gl_lds16(gB, (char*)Bs[0] + t * 16);
  __syncthreads();

  for (int step = 0; step < 16; ++step) {
    int cur = step & 1;
    if (step < 15) {
      int kt = (step + 1) * 32;
      gl_lds16(gA0 + kt, (char*)As[cur ^ 1] + sA0 * 16);
      gl_lds16(gA1 + kt, (char*)As[cur ^ 1] + sA1 * 16);
      gl_lds16(gB + kt, (char*)Bs[cur ^ 1] + t * 16);
    }
    short8 af[4], bfr[2];
#pragma unroll
    for (int mi = 0; mi < 4; ++mi)
      af[mi] = *(const short8*)(As[cur] + (wr + mi * 16 + mm) * 32 + kb);
#pragma unroll
    for (int ni = 0; ni < 2; ++ni)
      bfr[ni] = *(const short8*)(Bs[cur] + (wc + ni * 16 + mm) * 32 + kb);
#pragma unroll
    for (int mi = 0; mi < 4; ++mi)
#pragma unroll
      for (int ni = 0; ni < 2; ++ni)
        acc[mi][ni] = __builtin_amdgcn_mfma_f32_16x16x32_bf16(af[mi], bfr[ni], acc[mi][ni], 0, 0, 0);
    __syncthreads();
  }
  int r4 = (lane >> 4) * 4;
  int cc = lane & 15;
#pragma unroll
  for (int mi = 0; mi < 4; ++mi)
#pragma unroll
    for (int ni = 0; ni < 2; ++ni)
#pragma unroll
      for (int rr = 0; rr < 4; ++rr) {
        int grow = m0 + wr + mi * 16 + r4 + rr;
        int gcol = n0 + wc + ni * 16 + cc;
        Whb[(size_t)grow * 512 + gcol] = f32_to_bf16(acc[mi][ni][rr]);
      }
}

// -- k3b: sorted-ed walk (masks from vms_g) + 8-wide sparse PV + ELU ----------------
__global__ __launch_bounds__(256, 4) void k3_attn(const unsigned* __restrict__ vms_g,
                                                  const float* __restrict__ ss_g,
                                                  const float* __restrict__ es,
                                                  const uint2* __restrict__ edp,
                                                  const u16* __restrict__ Whb,
                                                  float* __restrict__ out) {
  __shared__ unsigned vms[4][64];
  __shared__ uint2 lst[4][64];                 // (j, pv bits), rank order
  int wv = threadIdx.x >> 6, lane = threadIdx.x & 63;
  int L = blockIdx.x;
  int xcd = L & 7, g = L >> 3;                 // XCD swizzle: one batch per 2 XCDs
  int r = (xcd >> 1) * 2048 + (xcd & 1) * 1024 + g * 4 + wv;
  int b = r >> 11;
  lst[wv][lane] = make_uint2(0u, 0u);          // pad: j=0, pv=0 (zero weight)
  vms[wv][lane] = vms_g[((size_t)r << 6) + lane];
  float ss = ss_g[r];
  float esi = es[r];
  const uint2* edpb = edp + ((size_t)b << 11);
  uint2 cd0 = edpb[lane];

  // candidate walk over batch-sorted ed: first 16 valid = top-16 (monotone in ed)
  unsigned long long lmlt = (1ull << lane) - 1ull;
  int cnt = 0;
#define WALK(CD)                                                            \
  {                                                                         \
    float edv = __uint_as_float((CD).x);                                    \
    int j = (int)(CD).y;                                                    \
    unsigned wd = vms[wv][(j >> 2) & 63];                                   \
    bool val = (wd >> (((j >> 8) << 2) | (j & 3))) & 1u;                    \
    unsigned long long mk = __ballot(val);                                  \
    float xx = esi + edv;                                                   \
    float el = fmaxf(xx, 0.2f * xx);                                        \
    float pv = __expf(el);                                                  \
    int rk = cnt + (int)__popcll(mk & lmlt);                                \
    if (val && rk < 64) lst[wv][rk] = make_uint2((CD).y, __float_as_uint(pv)); \
    cnt += (int)__popcll(mk);                                               \
  }
  WALK(cd0)                                    // iteration 0: covers ~99.9% of rows
  for (int c0 = 64; c0 < 2048 && cnt < 20; c0 += 64) {
    uint2 cd = edpb[c0 + lane];
    WALK(cd)
  }
#undef WALK
  if (cnt > 64) cnt = 64;

  const u16* WhB = Whb + ((size_t)b << 20);
  float4 acc0 = {0.f, 0.f, 0.f, 0.f}, acc1 = {0.f, 0.f, 0.f, 0.f};

#define FMA8(U, AV)                                              \
    acc0.x += (AV) * bfLO(U.x); acc0.y += (AV) * bfHI(U.x);      \
    acc0.z += (AV) * bfLO(U.y); acc0.w += (AV) * bfHI(U.y);      \
    acc1.x += (AV) * bfLO(U.z); acc1.y += (AV) * bfHI(U.z);      \
    acc1.z += (AV) * bfLO(U.w); acc1.w += (AV) * bfHI(U.w);

  // group A: ranks 0..7 (8 gathers in flight)
  float pwA[8];
  uint4 uA[8];
#pragma unroll
  for (int t = 0; t < 8; ++t) {
    uint2 lt = lst[wv][t];
    pwA[t] = __uint_as_float(lt.y);
    uA[t] = ((const uint4*)(WhB + ((size_t)lt.x << 9)))[lane];
  }
#pragma unroll
  for (int t = 0; t < 8; ++t) { FMA8(uA[t], pwA[t]) }

  // group B: ranks 8..15
  float pwB[8];
  uint4 uB[8];
#pragma unroll
  for (int t = 0; t < 8; ++t) {
    uint2 lt = lst[wv][t + 8];
    pwB[t] = __uint_as_float(lt.y);
    uB[t] = ((const uint4*)(WhB + ((size_t)lt.x << 9)))[lane];
  }
#pragma unroll
  for (int t = 0; t < 8; ++t) { FMA8(uB[t], pwB[t]) }

  // tie extras: sorted candidates past rank 15 with attention == kth are kept by ref
  float p16v = __uint_as_float(lst[wv][15].y);
  float akq = p16v / ss;                       // exact IEEE kth attention (uniform)
  for (int t2 = 16; t2 < cnt; ++t2) {          // wave-uniform, rare
    uint2 lt = lst[wv][t2];
    float pvt = __uint_as_float(lt.y);
    if ((pvt / ss) < akq) break;               // strictly below kth -> done (monotone)
    uint4 u = ((const uint4*)(WhB + ((size_t)lt.x << 9)))[lane];
    FMA8(u, pvt)
  }
#undef FMA8

  // out = elu(acc / ss)
  float rss = 1.0f / ss;
  float4 o0, o1;
  o0.x = acc0.x * rss; o0.y = acc0.y * rss; o0.z = acc0.z * rss; o0.w = acc0.w * rss;
  o1.x = acc1.x * rss; o1.y = acc1.y * rss; o1.z = acc1.z * rss; o1.w = acc1.w * rss;
  o0.x = o0.x > 0.f ? o0.x : (__expf(o0.x) - 1.0f);
  o0.y = o0.y > 0.f ? o0.y : (__expf(o0.y) - 1.0f);
  o0.z = o0.z > 0.f ? o0.z : (__expf(o0.z) - 1.0f);
  o0.w = o0.w > 0.f ? o0.w : (__expf(o0.w) - 1.0f);
  o1.x = o1.x > 0.f ? o1.x : (__expf(o1.x) - 1.0f);
  o1.y = o1.y > 0.f ? o1.y : (__expf(o1.y) - 1.0f);
  o1.z = o1.z > 0.f ? o1.z : (__expf(o1.z) - 1.0f);
  o1.w = o1.w > 0.f ? o1.w : (__expf(o1.w) - 1.0f);
  float* ob = out + ((size_t)r << 9) + lane * 8;
  *(float4*)(ob) = o0;
  *(float4*)(ob + 4) = o1;
}

extern "C" void kernel_launch(void* const* d_in, const int* in_sizes, int n_in,
                              void* d_out, int out_size, void* d_ws, size_t ws_size,
                              hipStream_t stream) {
  const float* h = (const float*)d_in[0];   // (4,2048,512) fp32
  const int* adj = (const int*)d_in[1];     // (4,2048,2048) int32
  const float* W = (const float*)d_in[2];   // (512,512) fp32
  const float* a = (const float*)d_in[3];   // (1024,) fp32
  float* out = (float*)d_out;               // (4,2048,512) fp32
  char* ws = (char*)d_ws;

  // workspace layout (~19.6 MB)
  u16* Whb = (u16*)(ws);                                // 8192*512*2 = 8,388,608
  u16* hbf = (u16*)(ws + 8388608);                      // 8192*512*2 = 8,388,608
  u16* Wt = (u16*)(ws + 16777216);                      // 512*512*2  =   524,288
  uint2* edp = (uint2*)(ws + 16777216 + 524288);        // 4*2048*8   =    65,536
  unsigned* vms_g = (unsigned*)(ws + 16777216 + 524288 + 65536);  // 8192*64*4 = 2,097,152
  float* es = (float*)(ws + 16777216 + 524288 + 65536 + 2097152);
  float* ed = es + 8192;
  float* w1 = ed + 8192;
  float* w2 = w1 + 512;
  float* ss_g = w2 + 512;                               // 8192*4

  hipLaunchKernelGGL(k0_prep, dim3(192), dim3(256), 0, stream, W, a, Wt, w1, w2);
  hipLaunchKernelGGL(k1_rows, dim3(2048), dim3(256), 0, stream, h, w1, w2, es, ed, hbf);
  hipLaunchKernelGGL(k2_gemm, dim3(2688), dim3(256), 0, stream, hbf, Wt, Whb, ed, edp,
                     adj, es, vms_g, ss_g);
  hipLaunchKernelGGL(k3_attn, dim3(2048), dim3(256), 0, stream, vms_g, ss_g, es, edp, Whb, out);
}

// Round 16
// 45.314 us; speedup vs baseline: 1.2069x; 1.2069x over previous
//
#include <hip/hip_runtime.h>

typedef unsigned short u16;
typedef short short8 __attribute__((ext_vector_type(8)));
typedef float f32x4 __attribute__((ext_vector_type(4)));

static __device__ __forceinline__ u16 f32_to_bf16(float f) {
  unsigned u = __float_as_uint(f);
  u += 0x7FFFu + ((u >> 16) & 1u);
  return (u16)(u >> 16);
}
static __device__ __forceinline__ float bfLO(unsigned v) { return __uint_as_float(v << 16); }
static __device__ __forceinline__ float bfHI(unsigned v) { return __uint_as_float(v & 0xFFFF0000u); }

static __device__ __forceinline__ void gl_lds16(const void* g, void* l) {
  __builtin_amdgcn_global_load_lds((const __attribute__((address_space(1))) void*)g,
                                   (__attribute__((address_space(3))) void*)l, 16, 0, 0);
}

// ---------------- k0: Wt = W^T (bf16) ; w1 = W@a1, w2 = W@a2 (fp32) ----------------
__global__ __launch_bounds__(256) void k0_prep(const float* __restrict__ W,
                                               const float* __restrict__ a,
                                               u16* __restrict__ Wt,
                                               float* __restrict__ w1,
                                               float* __restrict__ w2) {
  int bid = blockIdx.x;
  int t = threadIdx.x;
  if (bid < 64) {
    __shared__ float tile[64][65];
    int tx = (bid & 7) * 64;   // o (col) base
    int ty = (bid >> 3) * 64;  // k (row) base
    int rl = t >> 4;           // 0..15
    int cb = (t & 15) * 4;     // 0..60
#pragma unroll
    for (int p = 0; p < 4; ++p) {
      float4 v = *(const float4*)(W + (size_t)(ty + rl + p * 16) * 512 + tx + cb);
      tile[rl + p * 16][cb + 0] = v.x;
      tile[rl + p * 16][cb + 1] = v.y;
      tile[rl + p * 16][cb + 2] = v.z;
      tile[rl + p * 16][cb + 3] = v.w;
    }
    __syncthreads();
#pragma unroll
    for (int p = 0; p < 4; ++p) {
      int n = tx + rl + p * 16;
      ushort4 o;
      o.x = f32_to_bf16(tile[cb + 0][rl + p * 16]);
      o.y = f32_to_bf16(tile[cb + 1][rl + p * 16]);
      o.z = f32_to_bf16(tile[cb + 2][rl + p * 16]);
      o.w = f32_to_bf16(tile[cb + 3][rl + p * 16]);
      *(ushort4*)(Wt + (size_t)n * 512 + ty + cb) = o;
    }
  } else {
    int i = (bid - 64) * 4 + (t >> 6);
    int lane = t & 63;
    const float* row = W + (size_t)i * 512;
    float s1 = 0.f, s2 = 0.f;
#pragma unroll
    for (int q = 0; q < 2; ++q) {
      float4 wv = *(const float4*)(row + lane * 8 + q * 4);
      float4 x1 = *(const float4*)(a + lane * 8 + q * 4);
      float4 x2 = *(const float4*)(a + 512 + lane * 8 + q * 4);
      s1 += wv.x * x1.x + wv.y * x1.y + wv.z * x1.z + wv.w * x1.w;
      s2 += wv.x * x2.x + wv.y * x2.y + wv.z * x2.z + wv.w * x2.w;
    }
#pragma unroll
    for (int d = 32; d; d >>= 1) { s1 += __shfl_xor(s1, d); s2 += __shfl_xor(s2, d); }
    if (lane == 0) { w1[i] = s1; w2[i] = s2; }
  }
}

// ---------- k1: es/ed dots (fp32) + hbf = bf16(h), one wave per row ----------------
__global__ __launch_bounds__(256) void k1_rows(const float* __restrict__ h,
                                               const float* __restrict__ w1,
                                               const float* __restrict__ w2,
                                               float* __restrict__ es,
                                               float* __restrict__ ed,
                                               u16* __restrict__ hbf) {
  int r = blockIdx.x * 4 + (threadIdx.x >> 6);
  int lane = threadIdx.x & 63;
  const float* row = h + (size_t)r * 512 + lane * 8;
  float4 v0 = *(const float4*)(row);
  float4 v1 = *(const float4*)(row + 4);
  uint4 pk;
  pk.x = (unsigned)f32_to_bf16(v0.x) | ((unsigned)f32_to_bf16(v0.y) << 16);
  pk.y = (unsigned)f32_to_bf16(v0.z) | ((unsigned)f32_to_bf16(v0.w) << 16);
  pk.z = (unsigned)f32_to_bf16(v1.x) | ((unsigned)f32_to_bf16(v1.y) << 16);
  pk.w = (unsigned)f32_to_bf16(v1.z) | ((unsigned)f32_to_bf16(v1.w) << 16);
  *(uint4*)(hbf + (size_t)r * 512 + lane * 8) = pk;
  float4 x0 = *(const float4*)(w1 + lane * 8);
  float4 x1 = *(const float4*)(w1 + lane * 8 + 4);
  float4 y0 = *(const float4*)(w2 + lane * 8);
  float4 y1 = *(const float4*)(w2 + lane * 8 + 4);
  float s1 = v0.x * x0.x + v0.y * x0.y + v0.z * x0.z + v0.w * x0.w +
             v1.x * x1.x + v1.y * x1.y + v1.z * x1.z + v1.w * x1.w;
  float s2 = v0.x * y0.x + v0.y * y0.y + v0.z * y0.z + v0.w * y0.w +
             v1.x * y1.x + v1.y * y1.y + v1.z * y1.z + v1.w * y1.w;
#pragma unroll
  for (int d = 32; d; d >>= 1) { s1 += __shfl_xor(s1, d); s2 += __shfl_xor(s2, d); }
  if (lane == 0) { es[r] = s1; ed[r] = s2; }
}

// -- k2 fused: [0,512) GEMM | [512,640) ed-sort | [640,2688) adj scan (k3a) ---------
// No intra-launch dependencies: GEMM reads hbf/Wt writes Whb; sort reads ed writes
// edp; scan reads adj/es/ed writes vms_g/ss_g. The 67 MB adj stream overlaps the
// MFMA-bound GEMM (disjoint resources).
__global__ __launch_bounds__(256) void k2_gemm(const u16* __restrict__ hbf,
                                               const u16* __restrict__ Wt,
                                               u16* __restrict__ Whb,
                                               const float* __restrict__ ed,
                                               uint2* __restrict__ edp,
                                               const int* __restrict__ adj,
                                               const float* __restrict__ es,
                                               unsigned* __restrict__ vms_g,
                                               float* __restrict__ ss_g) {
  __shared__ __align__(16) u16 As[2][128 * 32];
  __shared__ __align__(16) u16 Bs[2][64 * 32];
  int t = threadIdx.x;
  int L = blockIdx.x;

  if (L >= 640) {
    // ---- k3a: adj scan -> validity masks + softmax denominator (no-max exp) ----
    int q = L - 640;           // 0..2047
    int wv = t >> 6, lane = t & 63;
    int xcd = q & 7, g = q >> 3;
    int r = (xcd >> 1) * 2048 + (xcd & 1) * 1024 + g * 4 + wv;
    int b = r >> 11;
    float esi = es[r];
    const int4* arow = (const int4*)(adj + ((size_t)r << 11));
    const float4* edr = (const float4*)(ed + ((size_t)b << 11));
    unsigned vm = 0;
    float ss = 0.f;
#pragma unroll
    for (int u = 0; u < 8; ++u) {
      int4 a4 = arow[u * 64 + lane];
      float4 e4 = edr[u * 64 + lane];
      float ee[4] = {e4.x, e4.y, e4.z, e4.w};
      int aa[4] = {a4.x, a4.y, a4.z, a4.w};
#pragma unroll
      for (int c = 0; c < 4; ++c) {
        float xx = esi + ee[c];
        float el = fmaxf(xx, 0.2f * xx);       // LeakyReLU(0.2); |e| <~ 20, exp safe
        bool valid = aa[c] > 0;
        vm |= (valid ? 1u : 0u) << (u * 4 + c);
        ss += valid ? __expf(el) : 0.f;
      }
    }
    vms_g[((size_t)r << 6) + lane] = vm;
#pragma unroll
    for (int d = 32; d; d >>= 1) ss += __shfl_xor(ss, d);
    if (lane == 0) ss_g[r] = ss;
    return;
  }

  if (L >= 512) {
    // ---- batch ed sort by wave-parallel rank-counting ----
    int q = L - 512;           // 0..127
    int bb = q >> 5;           // batch 0..3
    int seg = q & 31;          // 64-element i-segment
    int lane = t & 63, wvv = t >> 6;
    const float* edb = ed + bb * 2048;
    float4 vals[8];            // this lane's 32 j-values, register-resident
#pragma unroll
    for (int c = 0; c < 8; ++c) vals[c] = *(const float4*)(edb + c * 256 + lane * 4);
    float vk = edb[seg * 64 + wvv * 16 + (lane & 15)];   // prefetch 16 vi per wave
#pragma unroll 1
    for (int k = 0; k < 16; ++k) {
      int i = seg * 64 + wvv * 16 + k;
      float vi = __shfl(vk, k);
      int rank = 0;
#pragma unroll
      for (int c = 0; c < 8; ++c) {
        int jb = c * 256 + lane * 4;
        rank += (int)(vals[c].x > vi) + (int)((vals[c].x == vi) & (jb + 0 < i));
        rank += (int)(vals[c].y > vi) + (int)((vals[c].y == vi) & (jb + 1 < i));
        rank += (int)(vals[c].z > vi) + (int)((vals[c].z == vi) & (jb + 2 < i));
        rank += (int)(vals[c].w > vi) + (int)((vals[c].w == vi) & (jb + 3 < i));
      }
#pragma unroll
      for (int d = 32; d; d >>= 1) rank += __shfl_xor(rank, d);
      if (lane == 0) edp[bb * 2048 + rank] = make_uint2(__float_as_uint(vi), (unsigned)i);
    }
    return;
  }

  int lane = t & 63;
  int wv = t >> 6;
  int xcd = L & 7, g = L >> 3;                 // XCD swizzle: 8 n-blocks of one m on one XCD
  int m0 = (xcd * 8 + (g >> 3)) * 128;
  int n0 = (g & 7) * 64;
  int wr = (wv >> 1) * 64, wc = (wv & 1) * 32;
  f32x4 zero = {0.f, 0.f, 0.f, 0.f};
  f32x4 acc[4][2];
#pragma unroll
  for (int i = 0; i < 4; ++i)
#pragma unroll
    for (int j = 0; j < 2; ++j) acc[i][j] = zero;
  int kb = (lane >> 4) * 8;
  int mm = lane & 15;
  int sA0 = t, sA1 = t + 256;                  // A: 512 segs of 16B; B: 256 segs
  const u16* gA0 = hbf + (size_t)(m0 + (sA0 >> 2)) * 512 + (sA0 & 3) * 8;
  const u16* gA1 = hbf + (size_t)(m0 + (sA1 >> 2)) * 512 + (sA1 & 3) * 8;
  const u16* gB = Wt + (size_t)(n0 + (t >> 2)) * 512 + (t & 3) * 8;

  gl_lds16(gA0, (char*)As[0] + sA0 * 16);
  gl_lds16(gA1, (char*)As[0] + sA1 * 16);
  gl_lds16(gB, (char*)Bs[0] + t * 16);
  __syncthreads();

  for (int step = 0; step < 16; ++step) {
    int cur = step & 1;
    if (step < 15) {
      int kt = (step + 1) * 32;
      gl_lds16(gA0 + kt, (char*)As[cur ^ 1] + sA0 * 16);
      gl_lds16(gA1 + kt, (char*)As[cur ^ 1] + sA1 * 16);
      gl_lds16(gB + kt, (char*)Bs[cur ^ 1] + t * 16);
    }
    short8 af[4], bfr[2];
#pragma unroll
    for (int mi = 0; mi < 4; ++mi)
      af[mi] = *(const short8*)(As[cur] + (wr + mi * 16 + mm) * 32 + kb);
#pragma unroll
    for (int ni = 0; ni < 2; ++ni)
      bfr[ni] = *(const short8*)(Bs[cur] + (wc + ni * 16 + mm) * 32 + kb);
#pragma unroll
    for (int mi = 0; mi < 4; ++mi)
#pragma unroll
      for (int ni = 0; ni < 2; ++ni)
        acc[mi][ni] = __builtin_amdgcn_mfma_f32_16x16x32_bf16(af[mi], bfr[ni], acc[mi][ni], 0, 0, 0);
    __syncthreads();
  }
  int r4 = (lane >> 4) * 4;
  int cc = lane & 15;
#pragma unroll
  for (int mi = 0; mi < 4; ++mi)
#pragma unroll
    for (int ni = 0; ni < 2; ++ni)
#pragma unroll
      for (int rr = 0; rr < 4; ++rr) {
        int grow = m0 + wr + mi * 16 + r4 + rr;
        int gcol = n0 + wc + ni * 16 + cc;
        Whb[(size_t)grow * 512 + gcol] = f32_to_bf16(acc[mi][ni][rr]);
      }
}

// -- k3b: sorted-ed walk (masks from vms_g) + 8-wide sparse PV + ELU ----------------
__global__ __launch_bounds__(256, 4) void k3_attn(const unsigned* __restrict__ vms_g,
                                                  const float* __restrict__ ss_g,
                                                  const float* __restrict__ es,
                                                  const uint2* __restrict__ edp,
                                                  const u16* __restrict__ Whb,
                                                  float* __restrict__ out) {
  __shared__ unsigned vms[4][64];
  __shared__ uint2 lst[4][64];                 // (j, pv bits), rank order
  int wv = threadIdx.x >> 6, lane = threadIdx.x & 63;
  int L = blockIdx.x;
  int xcd = L & 7, g = L >> 3;                 // XCD swizzle: one batch per 2 XCDs
  int r = (xcd >> 1) * 2048 + (xcd & 1) * 1024 + g * 4 + wv;
  int b = r >> 11;
  lst[wv][lane] = make_uint2(0u, 0u);          // pad: j=0, pv=0 (zero weight)
  vms[wv][lane] = vms_g[((size_t)r << 6) + lane];
  float ss = ss_g[r];
  float esi = es[r];
  const uint2* edpb = edp + ((size_t)b << 11);
  uint2 cd0 = edpb[lane];

  // candidate walk over batch-sorted ed: first 16 valid = top-16 (monotone in ed)
  unsigned long long lmlt = (1ull << lane) - 1ull;
  int cnt = 0;
#define WALK(CD)                                                            \
  {                                                                         \
    float edv = __uint_as_float((CD).x);                                    \
    int j = (int)(CD).y;                                                    \
    unsigned wd = vms[wv][(j >> 2) & 63];                                   \
    bool val = (wd >> (((j >> 8) << 2) | (j & 3))) & 1u;                    \
    unsigned long long mk = __ballot(val);                                  \
    float xx = esi + edv;                                                   \
    float el = fmaxf(xx, 0.2f * xx);                                        \
    float pv = __expf(el);                                                  \
    int rk = cnt + (int)__popcll(mk & lmlt);                                \
    if (val && rk < 64) lst[wv][rk] = make_uint2((CD).y, __float_as_uint(pv)); \
    cnt += (int)__popcll(mk);                                               \
  }
  WALK(cd0)                                    // iteration 0: covers ~99.9% of rows
  for (int c0 = 64; c0 < 2048 && cnt < 20; c0 += 64) {
    uint2 cd = edpb[c0 + lane];
    WALK(cd)
  }
#undef WALK
  if (cnt > 64) cnt = 64;

  const u16* WhB = Whb + ((size_t)b << 20);
  float4 acc0 = {0.f, 0.f, 0.f, 0.f}, acc1 = {0.f, 0.f, 0.f, 0.f};

#define FMA8(U, AV)                                              \
    acc0.x += (AV) * bfLO(U.x); acc0.y += (AV) * bfHI(U.x);      \
    acc0.z += (AV) * bfLO(U.y); acc0.w += (AV) * bfHI(U.y);      \
    acc1.x += (AV) * bfLO(U.z); acc1.y += (AV) * bfHI(U.z);      \
    acc1.z += (AV) * bfLO(U.w); acc1.w += (AV) * bfHI(U.w);

  // group A: ranks 0..7 (8 gathers in flight)
  float pwA[8];
  uint4 uA[8];
#pragma unroll
  for (int t = 0; t < 8; ++t) {
    uint2 lt = lst[wv][t];
    pwA[t] = __uint_as_float(lt.y);
    uA[t] = ((const uint4*)(WhB + ((size_t)lt.x << 9)))[lane];
  }
#pragma unroll
  for (int t = 0; t < 8; ++t) { FMA8(uA[t], pwA[t]) }

  // group B: ranks 8..15
  float pwB[8];
  uint4 uB[8];
#pragma unroll
  for (int t = 0; t < 8; ++t) {
    uint2 lt = lst[wv][t + 8];
    pwB[t] = __uint_as_float(lt.y);
    uB[t] = ((const uint4*)(WhB + ((size_t)lt.x << 9)))[lane];
  }
#pragma unroll
  for (int t = 0; t < 8; ++t) { FMA8(uB[t], pwB[t]) }

  // tie extras: sorted candidates past rank 15 with attention == kth are kept by ref
  float p16v = __uint_as_float(lst[wv][15].y);
  float akq = p16v / ss;                       // exact IEEE kth attention (uniform)
  for (int t2 = 16; t2 < cnt; ++t2) {          // wave-uniform, rare
    uint2 lt = lst[wv][t2];
    float pvt = __uint_as_float(lt.y);
    if ((pvt / ss) < akq) break;               // strictly below kth -> done (monotone)
    uint4 u = ((const uint4*)(WhB + ((size_t)lt.x << 9)))[lane];
    FMA8(u, pvt)
  }
#undef FMA8

  // out = elu(acc / ss)
  float rss = 1.0f / ss;
  float4 o0, o1;
  o0.x = acc0.x * rss; o0.y = acc0.y * rss; o0.z = acc0.z * rss; o0.w = acc0.w * rss;
  o1.x = acc1.x * rss; o1.y = acc1.y * rss; o1.z = acc1.z * rss; o1.w = acc1.w * rss;
  o0.x = o0.x > 0.f ? o0.x : (__expf(o0.x) - 1.0f);
  o0.y = o0.y > 0.f ? o0.y : (__expf(o0.y) - 1.0f);
  o0.z = o0.z > 0.f ? o0.z : (__expf(o0.z) - 1.0f);
  o0.w = o0.w > 0.f ? o0.w : (__expf(o0.w) - 1.0f);
  o1.x = o1.x > 0.f ? o1.x : (__expf(o1.x) - 1.0f);
  o1.y = o1.y > 0.f ? o1.y : (__expf(o1.y) - 1.0f);
  o1.z = o1.z > 0.f ? o1.z : (__expf(o1.z) - 1.0f);
  o1.w = o1.w > 0.f ? o1.w : (__expf(o1.w) - 1.0f);
  float* ob = out + ((size_t)r << 9) + lane * 8;
  *(float4*)(ob) = o0;
  *(float4*)(ob + 4) = o1;
}

extern "C" void kernel_launch(void* const* d_in, const int* in_sizes, int n_in,
                              void* d_out, int out_size, void* d_ws, size_t ws_size,
                              hipStream_t stream) {
  const float* h = (const float*)d_in[0];   // (4,2048,512) fp32
  const int* adj = (const int*)d_in[1];     // (4,2048,2048) int32
  const float* W = (const float*)d_in[2];   // (512,512) fp32
  const float* a = (const float*)d_in[3];   // (1024,) fp32
  float* out = (float*)d_out;               // (4,2048,512) fp32
  char* ws = (char*)d_ws;

  // workspace layout (~19.6 MB)
  u16* Whb = (u16*)(ws);                                // 8192*512*2 = 8,388,608
  u16* hbf = (u16*)(ws + 8388608);                      // 8192*512*2 = 8,388,608
  u16* Wt = (u16*)(ws + 16777216);                      // 512*512*2  =   524,288
  uint2* edp = (uint2*)(ws + 16777216 + 524288);        // 4*2048*8   =    65,536
  unsigned* vms_g = (unsigned*)(ws + 16777216 + 524288 + 65536);  // 8192*64*4 = 2,097,152
  float* es = (float*)(ws + 16777216 + 524288 + 65536 + 2097152);
  float* ed = es + 8192;
  float* w1 = ed + 8192;
  float* w2 = w1 + 512;
  float* ss_g = w2 + 512;                               // 8192*4

  hipLaunchKernelGGL(k0_prep, dim3(192), dim3(256), 0, stream, W, a, Wt, w1, w2);
  hipLaunchKernelGGL(k1_rows, dim3(2048), dim3(256), 0, stream, h, w1, w2, es, ed, hbf);
  hipLaunchKernelGGL(k2_gemm, dim3(2688), dim3(256), 0, stream, hbf, Wt, Whb, ed, edp,
                     adj, es, vms_g, ss_g);
  hipLaunchKernelGGL(k3_attn, dim3(2048), dim3(256), 0, stream, vms_g, ss_g, es, edp, Whb, out);
}

// Round 17
// 45.129 us; speedup vs baseline: 1.2119x; 1.0041x over previous
//
#include <hip/hip_runtime.h>

typedef unsigned short u16;
typedef short short8 __attribute__((ext_vector_type(8)));
typedef float f32x4 __attribute__((ext_vector_type(4)));

static __device__ __forceinline__ u16 f32_to_bf16(float f) {
  unsigned u = __float_as_uint(f);
  u += 0x7FFFu + ((u >> 16) & 1u);
  return (u16)(u >> 16);
}
static __device__ __forceinline__ float bfLO(unsigned v) { return __uint_as_float(v << 16); }
static __device__ __forceinline__ float bfHI(unsigned v) { return __uint_as_float(v & 0xFFFF0000u); }

static __device__ __forceinline__ void gl_lds16(const void* g, void* l) {
  __builtin_amdgcn_global_load_lds((const __attribute__((address_space(1))) void*)g,
                                   (__attribute__((address_space(3))) void*)l, 16, 0, 0);
}

// ---------------- k0: w1 = W@a1, w2 = W@a2 (fp32) — 128 blocks only ----------------
__global__ __launch_bounds__(256) void k0_prep(const float* __restrict__ W,
                                               const float* __restrict__ a,
                                               float* __restrict__ w1,
                                               float* __restrict__ w2) {
  int i = blockIdx.x * 4 + (threadIdx.x >> 6);
  int lane = threadIdx.x & 63;
  const float* row = W + (size_t)i * 512;
  float s1 = 0.f, s2 = 0.f;
#pragma unroll
  for (int q = 0; q < 2; ++q) {
    float4 wv = *(const float4*)(row + lane * 8 + q * 4);
    float4 x1 = *(const float4*)(a + lane * 8 + q * 4);
    float4 x2 = *(const float4*)(a + 512 + lane * 8 + q * 4);
    s1 += wv.x * x1.x + wv.y * x1.y + wv.z * x1.z + wv.w * x1.w;
    s2 += wv.x * x2.x + wv.y * x2.y + wv.z * x2.z + wv.w * x2.w;
  }
#pragma unroll
  for (int d = 32; d; d >>= 1) { s1 += __shfl_xor(s1, d); s2 += __shfl_xor(s2, d); }
  if (lane == 0) { w1[i] = s1; w2[i] = s2; }
}

// -- k1: [0,2048) es/ed dots + hbf = bf16(h) | [2048,2112) Wt = W^T (bf16) ----------
// Transpose depends only on W (consumed by next launch) — no intra-launch deps.
__global__ __launch_bounds__(256) void k1_rows(const float* __restrict__ h,
                                               const float* __restrict__ w1,
                                               const float* __restrict__ w2,
                                               float* __restrict__ es,
                                               float* __restrict__ ed,
                                               u16* __restrict__ hbf,
                                               const float* __restrict__ W,
                                               u16* __restrict__ Wt) {
  int t = threadIdx.x;
  int L = blockIdx.x;
  if (L >= 2048) {
    // ---- Wt transpose (bf16), same tile scheme as old k0 ----
    __shared__ float tile[64][65];
    int bid = L - 2048;
    int tx = (bid & 7) * 64;   // o (col) base
    int ty = (bid >> 3) * 64;  // k (row) base
    int rl = t >> 4;           // 0..15
    int cb = (t & 15) * 4;     // 0..60
#pragma unroll
    for (int p = 0; p < 4; ++p) {
      float4 v = *(const float4*)(W + (size_t)(ty + rl + p * 16) * 512 + tx + cb);
      tile[rl + p * 16][cb + 0] = v.x;
      tile[rl + p * 16][cb + 1] = v.y;
      tile[rl + p * 16][cb + 2] = v.z;
      tile[rl + p * 16][cb + 3] = v.w;
    }
    __syncthreads();
#pragma unroll
    for (int p = 0; p < 4; ++p) {
      int n = tx + rl + p * 16;
      ushort4 o;
      o.x = f32_to_bf16(tile[cb + 0][rl + p * 16]);
      o.y = f32_to_bf16(tile[cb + 1][rl + p * 16]);
      o.z = f32_to_bf16(tile[cb + 2][rl + p * 16]);
      o.w = f32_to_bf16(tile[cb + 3][rl + p * 16]);
      *(ushort4*)(Wt + (size_t)n * 512 + ty + cb) = o;
    }
    return;
  }
  int r = L * 4 + (t >> 6);
  int lane = t & 63;
  const float* row = h + (size_t)r * 512 + lane * 8;
  float4 v0 = *(const float4*)(row);
  float4 v1 = *(const float4*)(row + 4);
  uint4 pk;
  pk.x = (unsigned)f32_to_bf16(v0.x) | ((unsigned)f32_to_bf16(v0.y) << 16);
  pk.y = (unsigned)f32_to_bf16(v0.z) | ((unsigned)f32_to_bf16(v0.w) << 16);
  pk.z = (unsigned)f32_to_bf16(v1.x) | ((unsigned)f32_to_bf16(v1.y) << 16);
  pk.w = (unsigned)f32_to_bf16(v1.z) | ((unsigned)f32_to_bf16(v1.w) << 16);
  *(uint4*)(hbf + (size_t)r * 512 + lane * 8) = pk;
  float4 x0 = *(const float4*)(w1 + lane * 8);
  float4 x1 = *(const float4*)(w1 + lane * 8 + 4);
  float4 y0 = *(const float4*)(w2 + lane * 8);
  float4 y1 = *(const float4*)(w2 + lane * 8 + 4);
  float s1 = v0.x * x0.x + v0.y * x0.y + v0.z * x0.z + v0.w * x0.w +
             v1.x * x1.x + v1.y * x1.y + v1.z * x1.z + v1.w * x1.w;
  float s2 = v0.x * y0.x + v0.y * y0.y + v0.z * y0.z + v0.w * y0.w +
             v1.x * y1.x + v1.y * y1.y + v1.z * y1.z + v1.w * y1.w;
#pragma unroll
  for (int d = 32; d; d >>= 1) { s1 += __shfl_xor(s1, d); s2 += __shfl_xor(s2, d); }
  if (lane == 0) { es[r] = s1; ed[r] = s2; }
}

// -- k2 fused: [0,512) GEMM | [512,640) ed-sort | [640,2688) adj scan (k3a) ---------
// No intra-launch dependencies: GEMM reads hbf/Wt writes Whb; sort reads ed writes
// edp; scan reads adj/es/ed writes vms_g/ss_g. The 67 MB adj stream overlaps the
// MFMA-bound GEMM (disjoint resources).
__global__ __launch_bounds__(256) void k2_gemm(const u16* __restrict__ hbf,
                                               const u16* __restrict__ Wt,
                                               u16* __restrict__ Whb,
                                               const float* __restrict__ ed,
                                               uint2* __restrict__ edp,
                                               const int* __restrict__ adj,
                                               const float* __restrict__ es,
                                               unsigned* __restrict__ vms_g,
                                               float* __restrict__ ss_g) {
  __shared__ __align__(16) u16 As[2][128 * 32];
  __shared__ __align__(16) u16 Bs[2][64 * 32];
  int t = threadIdx.x;
  int L = blockIdx.x;

  if (L >= 640) {
    // ---- k3a: adj scan -> validity masks + softmax denominator (no-max exp) ----
    int q = L - 640;           // 0..2047
    int wv = t >> 6, lane = t & 63;
    int xcd = q & 7, g = q >> 3;
    int r = (xcd >> 1) * 2048 + (xcd & 1) * 1024 + g * 4 + wv;
    int b = r >> 11;
    float esi = es[r];
    const int4* arow = (const int4*)(adj + ((size_t)r << 11));
    const float4* edr = (const float4*)(ed + ((size_t)b << 11));
    unsigned vm = 0;
    float ss = 0.f;
#pragma unroll
    for (int u = 0; u < 8; ++u) {
      int4 a4 = arow[u * 64 + lane];
      float4 e4 = edr[u * 64 + lane];
      float ee[4] = {e4.x, e4.y, e4.z, e4.w};
      int aa[4] = {a4.x, a4.y, a4.z, a4.w};
#pragma unroll
      for (int c = 0; c < 4; ++c) {
        float xx = esi + ee[c];
        float el = fmaxf(xx, 0.2f * xx);       // LeakyReLU(0.2); |e| <~ 20, exp safe
        bool valid = aa[c] > 0;
        vm |= (valid ? 1u : 0u) << (u * 4 + c);
        ss += valid ? __expf(el) : 0.f;
      }
    }
    vms_g[((size_t)r << 6) + lane] = vm;
#pragma unroll
    for (int d = 32; d; d >>= 1) ss += __shfl_xor(ss, d);
    if (lane == 0) ss_g[r] = ss;
    return;
  }

  if (L >= 512) {
    // ---- batch ed sort by wave-parallel rank-counting ----
    int q = L - 512;           // 0..127
    int bb = q >> 5;           // batch 0..3
    int seg = q & 31;          // 64-element i-segment
    int lane = t & 63, wvv = t >> 6;
    const float* edb = ed + bb * 2048;
    float4 vals[8];            // this lane's 32 j-values, register-resident
#pragma unroll
    for (int c = 0; c < 8; ++c) vals[c] = *(const float4*)(edb + c * 256 + lane * 4);
    float vk = edb[seg * 64 + wvv * 16 + (lane & 15)];   // prefetch 16 vi per wave
#pragma unroll 1
    for (int k = 0; k < 16; ++k) {
      int i = seg * 64 + wvv * 16 + k;
      float vi = __shfl(vk, k);
      int rank = 0;
#pragma unroll
      for (int c = 0; c < 8; ++c) {
        int jb = c * 256 + lane * 4;
        rank += (int)(vals[c].x > vi) + (int)((vals[c].x == vi) & (jb + 0 < i));
        rank += (int)(vals[c].y > vi) + (int)((vals[c].y == vi) & (jb + 1 < i));
        rank += (int)(vals[c].z > vi) + (int)((vals[c].z == vi) & (jb + 2 < i));
        rank += (int)(vals[c].w > vi) + (int)((vals[c].w == vi) & (jb + 3 < i));
      }
#pragma unroll
      for (int d = 32; d; d >>= 1) rank += __shfl_xor(rank, d);
      if (lane == 0) edp[bb * 2048 + rank] = make_uint2(__float_as_uint(vi), (unsigned)i);
    }
    return;
  }

  int lane = t & 63;
  int wv = t >> 6;
  int xcd = L & 7, g = L >> 3;                 // XCD swizzle: 8 n-blocks of one m on one XCD
  int m0 = (xcd * 8 + (g >> 3)) * 128;
  int n0 = (g & 7) * 64;
  int wr = (wv >> 1) * 64, wc = (wv & 1) * 32;
  f32x4 zero = {0.f, 0.f, 0.f, 0.f};
  f32x4 acc[4][2];
#pragma unroll
  for (int i = 0; i < 4; ++i)
#pragma unroll
    for (int j = 0; j < 2; ++j) acc[i][j] = zero;
  int kb = (lane >> 4) * 8;
  int mm = lane & 15;
  int sA0 = t, sA1 = t + 256;                  // A: 512 segs of 16B; B: 256 segs
  const u16* gA0 = hbf + (size_t)(m0 + (sA0 >> 2)) * 512 + (sA0 & 3) * 8;
  const u16* gA1 = hbf + (size_t)(m0 + (sA1 >> 2)) * 512 + (sA1 & 3) * 8;
  const u16* gB = Wt + (size_t)(n0 + (t >> 2)) * 512 + (t & 3) * 8;

  gl_lds16(gA0, (char*)As[0] + sA0 * 16);
  gl_lds16(gA1, (char*)As[0] + sA1 * 16);
  gl_lds16(gB, (char*)Bs[0] + t * 16);
  __syncthreads();

  for (int step = 0; step < 16; ++step) {
    int cur = step & 1;
    if (step < 15) {
      int kt = (step + 1) * 32;
      gl_lds16(gA0 + kt, (char*)As[cur ^ 1] + sA0 * 16);
      gl_lds16(gA1 + kt, (char*)As[cur ^ 1] + sA1 * 16);
      gl_lds16(gB + kt, (char*)Bs[cur ^ 1] + t * 16);
    }
    short8 af[4], bfr[2];
#pragma unroll
    for (int mi = 0; mi < 4; ++mi)
      af[mi] = *(const short8*)(As[cur] + (wr + mi * 16 + mm) * 32 + kb);
#pragma unroll
    for (int ni = 0; ni < 2; ++ni)
      bfr[ni] = *(const short8*)(Bs[cur] + (wc + ni * 16 + mm) * 32 + kb);
#pragma unroll
    for (int mi = 0; mi < 4; ++mi)
#pragma unroll
      for (int ni = 0; ni < 2; ++ni)
        acc[mi][ni] = __builtin_amdgcn_mfma_f32_16x16x32_bf16(af[mi], bfr[ni], acc[mi][ni], 0, 0, 0);
    __syncthreads();
  }
  int r4 = (lane >> 4) * 4;
  int cc = lane & 15;
#pragma unroll
  for (int mi = 0; mi < 4; ++mi)
#pragma unroll
    for (int ni = 0; ni < 2; ++ni)
#pragma unroll
      for (int rr = 0; rr < 4; ++rr) {
        int grow = m0 + wr + mi * 16 + r4 + rr;
        int gcol = n0 + wc + ni * 16 + cc;
        Whb[(size_t)grow * 512 + gcol] = f32_to_bf16(acc[mi][ni][rr]);
      }
}

// -- k3b: sorted-ed walk (masks from vms_g) + 8-wide sparse PV + ELU ----------------
__global__ __launch_bounds__(256, 4) void k3_attn(const unsigned* __restrict__ vms_g,
                                                  const float* __restrict__ ss_g,
                                                  const float* __restrict__ es,
                                                  const uint2* __restrict__ edp,
                                                  const u16* __restrict__ Whb,
                                                  float* __restrict__ out) {
  __shared__ unsigned vms[4][64];
  __shared__ uint2 lst[4][64];                 // (j, pv bits), rank order
  int wv = threadIdx.x >> 6, lane = threadIdx.x & 63;
  int L = blockIdx.x;
  int xcd = L & 7, g = L >> 3;                 // XCD swizzle: one batch per 2 XCDs
  int r = (xcd >> 1) * 2048 + (xcd & 1) * 1024 + g * 4 + wv;
  int b = r >> 11;
  lst[wv][lane] = make_uint2(0u, 0u);          // pad: j=0, pv=0 (zero weight)
  vms[wv][lane] = vms_g[((size_t)r << 6) + lane];
  float ss = ss_g[r];
  float esi = es[r];
  const uint2* edpb = edp + ((size_t)b << 11);
  uint2 cd0 = edpb[lane];

  // candidate walk over batch-sorted ed: first 16 valid = top-16 (monotone in ed)
  unsigned long long lmlt = (1ull << lane) - 1ull;
  int cnt = 0;
#define WALK(CD)                                                            \
  {                                                                         \
    float edv = __uint_as_float((CD).x);                                    \
    int j = (int)(CD).y;                                                    \
    unsigned wd = vms[wv][(j >> 2) & 63];                                   \
    bool val = (wd >> (((j >> 8) << 2) | (j & 3))) & 1u;                    \
    unsigned long long mk = __ballot(val);                                  \
    float xx = esi + edv;                                                   \
    float el = fmaxf(xx, 0.2f * xx);                                        \
    float pv = __expf(el);                                                  \
    int rk = cnt + (int)__popcll(mk & lmlt);                                \
    if (val && rk < 64) lst[wv][rk] = make_uint2((CD).y, __float_as_uint(pv)); \
    cnt += (int)__popcll(mk);                                               \
  }
  WALK(cd0)                                    // iteration 0: covers ~99.9% of rows
  for (int c0 = 64; c0 < 2048 && cnt < 20; c0 += 64) {
    uint2 cd = edpb[c0 + lane];
    WALK(cd)
  }
#undef WALK
  if (cnt > 64) cnt = 64;

  const u16* WhB = Whb + ((size_t)b << 20);
  float4 acc0 = {0.f, 0.f, 0.f, 0.f}, acc1 = {0.f, 0.f, 0.f, 0.f};

#define FMA8(U, AV)                                              \
    acc0.x += (AV) * bfLO(U.x); acc0.y += (AV) * bfHI(U.x);      \
    acc0.z += (AV) * bfLO(U.y); acc0.w += (AV) * bfHI(U.y);      \
    acc1.x += (AV) * bfLO(U.z); acc1.y += (AV) * bfHI(U.z);      \
    acc1.z += (AV) * bfLO(U.w); acc1.w += (AV) * bfHI(U.w);

  // group A: ranks 0..7 (8 gathers in flight)
  float pwA[8];
  uint4 uA[8];
#pragma unroll
  for (int t = 0; t < 8; ++t) {
    uint2 lt = lst[wv][t];
    pwA[t] = __uint_as_float(lt.y);
    uA[t] = ((const uint4*)(WhB + ((size_t)lt.x << 9)))[lane];
  }
#pragma unroll
  for (int t = 0; t < 8; ++t) { FMA8(uA[t], pwA[t]) }

  // group B: ranks 8..15
  float pwB[8];
  uint4 uB[8];
#pragma unroll
  for (int t = 0; t < 8; ++t) {
    uint2 lt = lst[wv][t + 8];
    pwB[t] = __uint_as_float(lt.y);
    uB[t] = ((const uint4*)(WhB + ((size_t)lt.x << 9)))[lane];
  }
#pragma unroll
  for (int t = 0; t < 8; ++t) { FMA8(uB[t], pwB[t]) }

  // tie extras: sorted candidates past rank 15 with attention == kth are kept by ref
  float p16v = __uint_as_float(lst[wv][15].y);
  float akq = p16v / ss;                       // exact IEEE kth attention (uniform)
  for (int t2 = 16; t2 < cnt; ++t2) {          // wave-uniform, rare
    uint2 lt = lst[wv][t2];
    float pvt = __uint_as_float(lt.y);
    if ((pvt / ss) < akq) break;               // strictly below kth -> done (monotone)
    uint4 u = ((const uint4*)(WhB + ((size_t)lt.x << 9)))[lane];
    FMA8(u, pvt)
  }
#undef FMA8

  // out = elu(acc / ss)
  float rss = 1.0f / ss;
  float4 o0, o1;
  o0.x = acc0.x * rss; o0.y = acc0.y * rss; o0.z = acc0.z * rss; o0.w = acc0.w * rss;
  o1.x = acc1.x * rss; o1.y = acc1.y * rss; o1.z = acc1.z * rss; o1.w = acc1.w * rss;
  o0.x = o0.x > 0.f ? o0.x : (__expf(o0.x) - 1.0f);
  o0.y = o0.y > 0.f ? o0.y : (__expf(o0.y) - 1.0f);
  o0.z = o0.z > 0.f ? o0.z : (__expf(o0.z) - 1.0f);
  o0.w = o0.w > 0.f ? o0.w : (__expf(o0.w) - 1.0f);
  o1.x = o1.x > 0.f ? o1.x : (__expf(o1.x) - 1.0f);
  o1.y = o1.y > 0.f ? o1.y : (__expf(o1.y) - 1.0f);
  o1.z = o1.z > 0.f ? o1.z : (__expf(o1.z) - 1.0f);
  o1.w = o1.w > 0.f ? o1.w : (__expf(o1.w) - 1.0f);
  float* ob = out + ((size_t)r << 9) + lane * 8;
  *(float4*)(ob) = o0;
  *(float4*)(ob + 4) = o1;
}

extern "C" void kernel_launch(void* const* d_in, const int* in_sizes, int n_in,
                              void* d_out, int out_size, void* d_ws, size_t ws_size,
                              hipStream_t stream) {
  const float* h = (const float*)d_in[0];   // (4,2048,512) fp32
  const int* adj = (const int*)d_in[1];     // (4,2048,2048) int32
  const float* W = (const float*)d_in[2];   // (512,512) fp32
  const float* a = (const float*)d_in[3];   // (1024,) fp32
  float* out = (float*)d_out;               // (4,2048,512) fp32
  char* ws = (char*)d_ws;

  // workspace layout (~19.6 MB)
  u16* Whb = (u16*)(ws);                                // 8192*512*2 = 8,388,608
  u16* hbf = (u16*)(ws + 8388608);                      // 8192*512*2 = 8,388,608
  u16* Wt = (u16*)(ws + 16777216);                      // 512*512*2  =   524,288
  uint2* edp = (uint2*)(ws + 16777216 + 524288);        // 4*2048*8   =    65,536
  unsigned* vms_g = (unsigned*)(ws + 16777216 + 524288 + 65536);  // 8192*64*4 = 2,097,152
  float* es = (float*)(ws + 16777216 + 524288 + 65536 + 2097152);
  float* ed = es + 8192;
  float* w1 = ed + 8192;
  float* w2 = w1 + 512;
  float* ss_g = w2 + 512;                               // 8192*4

  hipLaunchKernelGGL(k0_prep, dim3(128), dim3(256), 0, stream, W, a, w1, w2);
  hipLaunchKernelGGL(k1_rows, dim3(2112), dim3(256), 0, stream, h, w1, w2, es, ed, hbf, W, Wt);
  hipLaunchKernelGGL(k2_gemm, dim3(2688), dim3(256), 0, stream, hbf, Wt, Whb, ed, edp,
                     adj, es, vms_g, ss_g);
  hipLaunchKernelGGL(k3_attn, dim3(2048), dim3(256), 0, stream, vms_g, ss_g, es, edp, Whb, out);
}

// Round 18
// 44.178 us; speedup vs baseline: 1.2379x; 1.0215x over previous
//
#include <hip/hip_runtime.h>

typedef unsigned short u16;
typedef short short8 __attribute__((ext_vector_type(8)));
typedef float f32x4 __attribute__((ext_vector_type(4)));

static __device__ __forceinline__ u16 f32_to_bf16(float f) {
  unsigned u = __float_as_uint(f);
  u += 0x7FFFu + ((u >> 16) & 1u);
  return (u16)(u >> 16);
}
static __device__ __forceinline__ float bfLO(unsigned v) { return __uint_as_float(v << 16); }
static __device__ __forceinline__ float bfHI(unsigned v) { return __uint_as_float(v & 0xFFFF0000u); }

static __device__ __forceinline__ void gl_lds16(const void* g, void* l) {
  __builtin_amdgcn_global_load_lds((const __attribute__((address_space(1))) void*)g,
                                   (__attribute__((address_space(3))) void*)l, 16, 0, 0);
}

// ---------------- k0: w1 = W@a1, w2 = W@a2 (fp32) — 128 blocks only ----------------
__global__ __launch_bounds__(256) void k0_prep(const float* __restrict__ W,
                                               const float* __restrict__ a,
                                               float* __restrict__ w1,
                                               float* __restrict__ w2) {
  int i = blockIdx.x * 4 + (threadIdx.x >> 6);
  int lane = threadIdx.x & 63;
  const float* row = W + (size_t)i * 512;
  float s1 = 0.f, s2 = 0.f;
#pragma unroll
  for (int q = 0; q < 2; ++q) {
    float4 wv = *(const float4*)(row + lane * 8 + q * 4);
    float4 x1 = *(const float4*)(a + lane * 8 + q * 4);
    float4 x2 = *(const float4*)(a + 512 + lane * 8 + q * 4);
    s1 += wv.x * x1.x + wv.y * x1.y + wv.z * x1.z + wv.w * x1.w;
    s2 += wv.x * x2.x + wv.y * x2.y + wv.z * x2.z + wv.w * x2.w;
  }
#pragma unroll
  for (int d = 32; d; d >>= 1) { s1 += __shfl_xor(s1, d); s2 += __shfl_xor(s2, d); }
  if (lane == 0) { w1[i] = s1; w2[i] = s2; }
}

// -- k1: [0,2048) es/ed dots + hbf = bf16(h) | [2048,2112) Wt = W^T (bf16) ----------
__global__ __launch_bounds__(256) void k1_rows(const float* __restrict__ h,
                                               const float* __restrict__ w1,
                                               const float* __restrict__ w2,
                                               float* __restrict__ es,
                                               float* __restrict__ ed,
                                               u16* __restrict__ hbf,
                                               const float* __restrict__ W,
                                               u16* __restrict__ Wt) {
  int t = threadIdx.x;
  int L = blockIdx.x;
  if (L >= 2048) {
    __shared__ float tile[64][65];
    int bid = L - 2048;
    int tx = (bid & 7) * 64;   // o (col) base
    int ty = (bid >> 3) * 64;  // k (row) base
    int rl = t >> 4;           // 0..15
    int cb = (t & 15) * 4;     // 0..60
#pragma unroll
    for (int p = 0; p < 4; ++p) {
      float4 v = *(const float4*)(W + (size_t)(ty + rl + p * 16) * 512 + tx + cb);
      tile[rl + p * 16][cb + 0] = v.x;
      tile[rl + p * 16][cb + 1] = v.y;
      tile[rl + p * 16][cb + 2] = v.z;
      tile[rl + p * 16][cb + 3] = v.w;
    }
    __syncthreads();
#pragma unroll
    for (int p = 0; p < 4; ++p) {
      int n = tx + rl + p * 16;
      ushort4 o;
      o.x = f32_to_bf16(tile[cb + 0][rl + p * 16]);
      o.y = f32_to_bf16(tile[cb + 1][rl + p * 16]);
      o.z = f32_to_bf16(tile[cb + 2][rl + p * 16]);
      o.w = f32_to_bf16(tile[cb + 3][rl + p * 16]);
      *(ushort4*)(Wt + (size_t)n * 512 + ty + cb) = o;
    }
    return;
  }
  int r = L * 4 + (t >> 6);
  int lane = t & 63;
  const float* row = h + (size_t)r * 512 + lane * 8;
  float4 v0 = *(const float4*)(row);
  float4 v1 = *(const float4*)(row + 4);
  uint4 pk;
  pk.x = (unsigned)f32_to_bf16(v0.x) | ((unsigned)f32_to_bf16(v0.y) << 16);
  pk.y = (unsigned)f32_to_bf16(v0.z) | ((unsigned)f32_to_bf16(v0.w) << 16);
  pk.z = (unsigned)f32_to_bf16(v1.x) | ((unsigned)f32_to_bf16(v1.y) << 16);
  pk.w = (unsigned)f32_to_bf16(v1.z) | ((unsigned)f32_to_bf16(v1.w) << 16);
  *(uint4*)(hbf + (size_t)r * 512 + lane * 8) = pk;
  float4 x0 = *(const float4*)(w1 + lane * 8);
  float4 x1 = *(const float4*)(w1 + lane * 8 + 4);
  float4 y0 = *(const float4*)(w2 + lane * 8);
  float4 y1 = *(const float4*)(w2 + lane * 8 + 4);
  float s1 = v0.x * x0.x + v0.y * x0.y + v0.z * x0.z + v0.w * x0.w +
             v1.x * x1.x + v1.y * x1.y + v1.z * x1.z + v1.w * x1.w;
  float s2 = v0.x * y0.x + v0.y * y0.y + v0.z * y0.z + v0.w * y0.w +
             v1.x * y1.x + v1.y * y1.y + v1.z * y1.z + v1.w * y1.w;
#pragma unroll
  for (int d = 32; d; d >>= 1) { s1 += __shfl_xor(s1, d); s2 += __shfl_xor(s2, d); }
  if (lane == 0) { es[r] = s1; ed[r] = s2; }
}

// -- k2 fused: [0,512) GEMM | [512,640) ed-sort | [640,2688) adj scan (k3a) ---------
// GEMM-first dispatch order (R14/R16 proven). Scan branch: all 16 loads prefetched
// into registers before compute (isolated R15 MLP change).
__global__ __launch_bounds__(256) void k2_gemm(const u16* __restrict__ hbf,
                                               const u16* __restrict__ Wt,
                                               u16* __restrict__ Whb,
                                               const float* __restrict__ ed,
                                               uint2* __restrict__ edp,
                                               const int* __restrict__ adj,
                                               const float* __restrict__ es,
                                               unsigned* __restrict__ vms_g,
                                               float* __restrict__ ss_g) {
  __shared__ __align__(16) u16 As[2][128 * 32];
  __shared__ __align__(16) u16 Bs[2][64 * 32];
  int t = threadIdx.x;
  int L = blockIdx.x;

  if (L >= 640) {
    // ---- k3a: adj scan -> validity masks + softmax denominator (no-max exp) ----
    // All 16 loads issued into registers BEFORE compute: max memory-level parallelism.
    int q = L - 640;           // 0..2047
    int wv = t >> 6, lane = t & 63;
    int xcd = q & 7, g = q >> 3;
    int r = (xcd >> 1) * 2048 + (xcd & 1) * 1024 + g * 4 + wv;
    int b = r >> 11;
    float esi = es[r];
    const int4* arow = (const int4*)(adj + ((size_t)r << 11));
    const float4* edr = (const float4*)(ed + ((size_t)b << 11));
    int4 a4[8];
    float4 e4[8];
#pragma unroll
    for (int u = 0; u < 8; ++u) a4[u] = arow[u * 64 + lane];
#pragma unroll
    for (int u = 0; u < 8; ++u) e4[u] = edr[u * 64 + lane];
    unsigned vm = 0;
    float ss = 0.f;
#pragma unroll
    for (int u = 0; u < 8; ++u) {
      float ee[4] = {e4[u].x, e4[u].y, e4[u].z, e4[u].w};
      int aa[4] = {a4[u].x, a4[u].y, a4[u].z, a4[u].w};
#pragma unroll
      for (int c = 0; c < 4; ++c) {
        float xx = esi + ee[c];
        float el = fmaxf(xx, 0.2f * xx);       // LeakyReLU(0.2); |e| <~ 20, exp safe
        bool valid = aa[c] > 0;
        vm |= (valid ? 1u : 0u) << (u * 4 + c);
        ss += valid ? __expf(el) : 0.f;
      }
    }
    vms_g[((size_t)r << 6) + lane] = vm;
#pragma unroll
    for (int d = 32; d; d >>= 1) ss += __shfl_xor(ss, d);
    if (lane == 0) ss_g[r] = ss;
    return;
  }

  if (L >= 512) {
    // ---- batch ed sort by wave-parallel rank-counting ----
    int q = L - 512;           // 0..127
    int bb = q >> 5;           // batch 0..3
    int seg = q & 31;          // 64-element i-segment
    int lane = t & 63, wvv = t >> 6;
    const float* edb = ed + bb * 2048;
    float4 vals[8];            // this lane's 32 j-values, register-resident
#pragma unroll
    for (int c = 0; c < 8; ++c) vals[c] = *(const float4*)(edb + c * 256 + lane * 4);
    float vk = edb[seg * 64 + wvv * 16 + (lane & 15)];   // prefetch 16 vi per wave
#pragma unroll 1
    for (int k = 0; k < 16; ++k) {
      int i = seg * 64 + wvv * 16 + k;
      float vi = __shfl(vk, k);
      int rank = 0;
#pragma unroll
      for (int c = 0; c < 8; ++c) {
        int jb = c * 256 + lane * 4;
        rank += (int)(vals[c].x > vi) + (int)((vals[c].x == vi) & (jb + 0 < i));
        rank += (int)(vals[c].y > vi) + (int)((vals[c].y == vi) & (jb + 1 < i));
        rank += (int)(vals[c].z > vi) + (int)((vals[c].z == vi) & (jb + 2 < i));
        rank += (int)(vals[c].w > vi) + (int)((vals[c].w == vi) & (jb + 3 < i));
      }
#pragma unroll
      for (int d = 32; d; d >>= 1) rank += __shfl_xor(rank, d);
      if (lane == 0) edp[bb * 2048 + rank] = make_uint2(__float_as_uint(vi), (unsigned)i);
    }
    return;
  }

  int lane = t & 63;
  int wv = t >> 6;
  int xcd = L & 7, g = L >> 3;                 // XCD swizzle: 8 n-blocks of one m on one XCD
  int m0 = (xcd * 8 + (g >> 3)) * 128;
  int n0 = (g & 7) * 64;
  int wr = (wv >> 1) * 64, wc = (wv & 1) * 32;
  f32x4 zero = {0.f, 0.f, 0.f, 0.f};
  f32x4 acc[4][2];
#pragma unroll
  for (int i = 0; i < 4; ++i)
#pragma unroll
    for (int j = 0; j < 2; ++j) acc[i][j] = zero;
  int kb = (lane >> 4) * 8;
  int mm = lane & 15;
  int sA0 = t, sA1 = t + 256;                  // A: 512 segs of 16B; B: 256 segs
  const u16* gA0 = hbf + (size_t)(m0 + (sA0 >> 2)) * 512 + (sA0 & 3) * 8;
  const u16* gA1 = hbf + (size_t)(m0 + (sA1 >> 2)) * 512 + (sA1 & 3) * 8;
  const u16* gB = Wt + (size_t)(n0 + (t >> 2)) * 512 + (t & 3) * 8;

  gl_lds16(gA0, (char*)As[0] + sA0 * 16);
  gl_lds16(gA1, (char*)As[0] + sA1 * 16);
  gl_lds16(gB, (char*)Bs[0] + t * 16);
  __syncthreads();

  for (int step = 0; step < 16; ++step) {
    int cur = step & 1;
    if (step < 15) {
      int kt = (step + 1) * 32;
      gl_lds16(gA0 + kt, (char*)As[cur ^ 1] + sA0 * 16);
      gl_lds16(gA1 + kt, (char*)As[cur ^ 1] + sA1 * 16);
      gl_lds16(gB + kt, (char*)Bs[cur ^ 1] + t * 16);
    }
    short8 af[4], bfr[2];
#pragma unroll
    for (int mi = 0; mi < 4; ++mi)
      af[mi] = *(const short8*)(As[cur] + (wr + mi * 16 + mm) * 32 + kb);
#pragma unroll
    for (int ni = 0; ni < 2; ++ni)
      bfr[ni] = *(const short8*)(Bs[cur] + (wc + ni * 16 + mm) * 32 + kb);
#pragma unroll
    for (int mi = 0; mi < 4; ++mi)
#pragma unroll
      for (int ni = 0; ni < 2; ++ni)
        acc[mi][ni] = __builtin_amdgcn_mfma_f32_16x16x32_bf16(af[mi], bfr[ni], acc[mi][ni], 0, 0, 0);
    __syncthreads();
  }
  int r4 = (lane >> 4) * 4;
  int cc = lane & 15;
#pragma unroll
  for (int mi = 0; mi < 4; ++mi)
#pragma unroll
    for (int ni = 0; ni < 2; ++ni)
#pragma unroll
      for (int rr = 0; rr < 4; ++rr) {
        int grow = m0 + wr + mi * 16 + r4 + rr;
        int gcol = n0 + wc + ni * 16 + cc;
        Whb[(size_t)grow * 512 + gcol] = f32_to_bf16(acc[mi][ni][rr]);
      }
}

// -- k3b: sorted-ed walk (masks from vms_g) + 8-wide sparse PV + ELU ----------------
__global__ __launch_bounds__(256, 4) void k3_attn(const unsigned* __restrict__ vms_g,
                                                  const float* __restrict__ ss_g,
                                                  const float* __restrict__ es,
                                                  const uint2* __restrict__ edp,
                                                  const u16* __restrict__ Whb,
                                                  float* __restrict__ out) {
  __shared__ unsigned vms[4][64];
  __shared__ uint2 lst[4][64];                 // (j, pv bits), rank order
  int wv = threadIdx.x >> 6, lane = threadIdx.x & 63;
  int L = blockIdx.x;
  int xcd = L & 7, g = L >> 3;                 // XCD swizzle: one batch per 2 XCDs
  int r = (xcd >> 1) * 2048 + (xcd & 1) * 1024 + g * 4 + wv;
  int b = r >> 11;
  lst[wv][lane] = make_uint2(0u, 0u);          // pad: j=0, pv=0 (zero weight)
  vms[wv][lane] = vms_g[((size_t)r << 6) + lane];
  float ss = ss_g[r];
  float esi = es[r];
  const uint2* edpb = edp + ((size_t)b << 11);
  uint2 cd0 = edpb[lane];

  // candidate walk over batch-sorted ed: first 16 valid = top-16 (monotone in ed)
  unsigned long long lmlt = (1ull << lane) - 1ull;
  int cnt = 0;
#define WALK(CD)                                                            \
  {                                                                         \
    float edv = __uint_as_float((CD).x);                                    \
    int j = (int)(CD).y;                                                    \
    unsigned wd = vms[wv][(j >> 2) & 63];                                   \
    bool val = (wd >> (((j >> 8) << 2) | (j & 3))) & 1u;                    \
    unsigned long long mk = __ballot(val);                                  \
    float xx = esi + edv;                                                   \
    float el = fmaxf(xx, 0.2f * xx);                                        \
    float pv = __expf(el);                                                  \
    int rk = cnt + (int)__popcll(mk & lmlt);                                \
    if (val && rk < 64) lst[wv][rk] = make_uint2((CD).y, __float_as_uint(pv)); \
    cnt += (int)__popcll(mk);                                               \
  }
  WALK(cd0)                                    // iteration 0: covers ~99.9% of rows
  for (int c0 = 64; c0 < 2048 && cnt < 20; c0 += 64) {
    uint2 cd = edpb[c0 + lane];
    WALK(cd)
  }
#undef WALK
  if (cnt > 64) cnt = 64;

  const u16* WhB = Whb + ((size_t)b << 20);
  float4 acc0 = {0.f, 0.f, 0.f, 0.f}, acc1 = {0.f, 0.f, 0.f, 0.f};

#define FMA8(U, AV)                                              \
    acc0.x += (AV) * bfLO(U.x); acc0.y += (AV) * bfHI(U.x);      \
    acc0.z += (AV) * bfLO(U.y); acc0.w += (AV) * bfHI(U.y);      \
    acc1.x += (AV) * bfLO(U.z); acc1.y += (AV) * bfHI(U.z);      \
    acc1.z += (AV) * bfLO(U.w); acc1.w += (AV) * bfHI(U.w);

  // group A: ranks 0..7 (8 gathers in flight)
  float pwA[8];
  uint4 uA[8];
#pragma unroll
  for (int t = 0; t < 8; ++t) {
    uint2 lt = lst[wv][t];
    pwA[t] = __uint_as_float(lt.y);
    uA[t] = ((const uint4*)(WhB + ((size_t)lt.x << 9)))[lane];
  }
#pragma unroll
  for (int t = 0; t < 8; ++t) { FMA8(uA[t], pwA[t]) }

  // group B: ranks 8..15
  float pwB[8];
  uint4 uB[8];
#pragma unroll
  for (int t = 0; t < 8; ++t) {
    uint2 lt = lst[wv][t + 8];
    pwB[t] = __uint_as_float(lt.y);
    uB[t] = ((const uint4*)(WhB + ((size_t)lt.x << 9)))[lane];
  }
#pragma unroll
  for (int t = 0; t < 8; ++t) { FMA8(uB[t], pwB[t]) }

  // tie extras: sorted candidates past rank 15 with attention == kth are kept by ref
  float p16v = __uint_as_float(lst[wv][15].y);
  float akq = p16v / ss;                       // exact IEEE kth attention (uniform)
  for (int t2 = 16; t2 < cnt; ++t2) {          // wave-uniform, rare
    uint2 lt = lst[wv][t2];
    float pvt = __uint_as_float(lt.y);
    if ((pvt / ss) < akq) break;               // strictly below kth -> done (monotone)
    uint4 u = ((const uint4*)(WhB + ((size_t)lt.x << 9)))[lane];
    FMA8(u, pvt)
  }
#undef FMA8

  // out = elu(acc / ss)
  float rss = 1.0f / ss;
  float4 o0, o1;
  o0.x = acc0.x * rss; o0.y = acc0.y * rss; o0.z = acc0.z * rss; o0.w = acc0.w * rss;
  o1.x = acc1.x * rss; o1.y = acc1.y * rss; o1.z = acc1.z * rss; o1.w = acc1.w * rss;
  o0.x = o0.x > 0.f ? o0.x : (__expf(o0.x) - 1.0f);
  o0.y = o0.y > 0.f ? o0.y : (__expf(o0.y) - 1.0f);
  o0.z = o0.z > 0.f ? o0.z : (__expf(o0.z) - 1.0f);
  o0.w = o0.w > 0.f ? o0.w : (__expf(o0.w) - 1.0f);
  o1.x = o1.x > 0.f ? o1.x : (__expf(o1.x) - 1.0f);
  o1.y = o1.y > 0.f ? o1.y : (__expf(o1.y) - 1.0f);
  o1.z = o1.z > 0.f ? o1.z : (__expf(o1.z) - 1.0f);
  o1.w = o1.w > 0.f ? o1.w : (__expf(o1.w) - 1.0f);
  float* ob = out + ((size_t)r << 9) + lane * 8;
  *(float4*)(ob) = o0;
  *(float4*)(ob + 4) = o1;
}

extern "C" void kernel_launch(void* const* d_in, const int* in_sizes, int n_in,
                              void* d_out, int out_size, void* d_ws, size_t ws_size,
                              hipStream_t stream) {
  const float* h = (const float*)d_in[0];   // (4,2048,512) fp32
  const int* adj = (const int*)d_in[1];     // (4,2048,2048) int32
  const float* W = (const float*)d_in[2];   // (512,512) fp32
  const float* a = (const float*)d_in[3];   // (1024,) fp32
  float* out = (float*)d_out;               // (4,2048,512) fp32
  char* ws = (char*)d_ws;

  // workspace layout (~19.6 MB)
  u16* Whb = (u16*)(ws);                                // 8192*512*2 = 8,388,608
  u16* hbf = (u16*)(ws + 8388608);                      // 8192*512*2 = 8,388,608
  u16* Wt = (u16*)(ws + 16777216);                      // 512*512*2  =   524,288
  uint2* edp = (uint2*)(ws + 16777216 + 524288);        // 4*2048*8   =    65,536
  unsigned* vms_g = (unsigned*)(ws + 16777216 + 524288 + 65536);  // 8192*64*4 = 2,097,152
  float* es = (float*)(ws + 16777216 + 524288 + 65536 + 2097152);
  float* ed = es + 8192;
  float* w1 = ed + 8192;
  float* w2 = w1 + 512;
  float* ss_g = w2 + 512;                               // 8192*4

  hipLaunchKernelGGL(k0_prep, dim3(128), dim3(256), 0, stream, W, a, w1, w2);
  hipLaunchKernelGGL(k1_rows, dim3(2112), dim3(256), 0, stream, h, w1, w2, es, ed, hbf, W, Wt);
  hipLaunchKernelGGL(k2_gemm, dim3(2688), dim3(256), 0, stream, hbf, Wt, Whb, ed, edp,
                     adj, es, vms_g, ss_g);
  hipLaunchKernelGGL(k3_attn, dim3(2048), dim3(256), 0, stream, vms_g, ss_g, es, edp, Whb, out);
}